// Round 16
// baseline (1300.311 us; speedup 1.0000x reference)
//
#include <hip/hip_runtime.h>
#include <cmath>

#define NTOK 65536
#define DMOD 1024
#define NEXP 64
#define TOPK 8
#define BTOK 64                  // tokens per block
#define KCH  64                  // k-chunk of h staged in LDS
#define NCH  (DMOD / KCH)        // 16 chunks
#define STR  65                  // odd stride

// token_mask may arrive as 1-byte bool or int32; sniff from the first word.
__device__ __forceinline__ bool tok_mask(const void* tm, int t, int mmode) {
    return mmode == 0 ? (((const unsigned char*)tm)[t] != 0)
                      : (((const unsigned int*)tm)[t] != 0u);
}

__global__ __launch_bounds__(256, 4)
void router_v16(const float* __restrict__ h,
                const float* __restrict__ W,
                const void* __restrict__ tmask,
                float* __restrict__ out)
{
    __shared__ __align__(16) float h_s[BTOK][STR];   // 16.6 KB; ls aliases after compute
    __shared__ float sm_m0[BTOK], sm_inv[BTOK];
    __shared__ unsigned long long mb[BTOK];

    float (*ls)[STR] = h_s;                   // epilogue alias (h tile dead by then)

    const int tid  = threadIdx.x;
    const int lane = tid & 63;
    const int wave = tid >> 6;
    const int tt   = tid & 15;                // token group: rows 4tt..4tt+3
    const int ee   = tid >> 4;                // expert group: rows 4ee..4ee+3
    const int t0   = blockIdx.x * BTOK;

    const unsigned int mw = *(const unsigned int*)tmask;
    const int mmode = (mw == 0x01010101u) ? 0 : 1;

    // this thread's 4 expert rows (read straight from global; L1-resident)
    const float* __restrict__ w0 = W + ((size_t)(ee * 4 + 0) << 10);
    const float* __restrict__ w1 = W + ((size_t)(ee * 4 + 1) << 10);
    const float* __restrict__ w2 = W + ((size_t)(ee * 4 + 2) << 10);
    const float* __restrict__ w3 = W + ((size_t)(ee * 4 + 3) << 10);

    // strict sequential fp32 FMA per output, k ascending (np-ref-matching order)
    float acc[4][4];
#pragma unroll
    for (int i = 0; i < 4; ++i)
#pragma unroll
        for (int j = 0; j < 4; ++j) acc[i][j] = 0.f;

    const int sr = tid >> 4;                  // staging row offset 0..15
    const int sc = (tid & 15) * 4;            // staging col 0..60

    for (int c = 0; c < NCH; ++c) {
        const int kc = c * KCH;

        // ---- stage h tile only: 4 coalesced global float4 loads, 4 LDS writes ----
        float4 ht[4];
#pragma unroll
        for (int p = 0; p < 4; ++p)
            ht[p] = *reinterpret_cast<const float4*>(
                h + (size_t)(t0 + p * 16 + sr) * DMOD + kc + sc);
#pragma unroll
        for (int p = 0; p < 4; ++p)
            *reinterpret_cast<float4*>(&h_s[p * 16 + sr][sc]) = ht[p];
        __syncthreads();

        // ---- compute: per 4-k window: 4 ds_read_b128 (h) + 4 global float4 (W) + 64 FMA ----
#pragma unroll
        for (int k4 = 0; k4 < KCH / 4; ++k4) {
            const int k = kc + k4 * 4;
            float4 hv[4], wv[4];
#pragma unroll
            for (int i = 0; i < 4; ++i)
                hv[i] = *reinterpret_cast<const float4*>(&h_s[tt * 4 + i][k4 * 4]);
            wv[0] = *reinterpret_cast<const float4*>(w0 + k);
            wv[1] = *reinterpret_cast<const float4*>(w1 + k);
            wv[2] = *reinterpret_cast<const float4*>(w2 + k);
            wv[3] = *reinterpret_cast<const float4*>(w3 + k);
#pragma unroll
            for (int i = 0; i < 4; ++i) {
#pragma unroll
                for (int j = 0; j < 4; ++j) {
                    float a = acc[i][j];
                    a = fmaf(hv[i].x, wv[j].x, a);
                    a = fmaf(hv[i].y, wv[j].y, a);
                    a = fmaf(hv[i].z, wv[j].z, a);
                    a = fmaf(hv[i].w, wv[j].w, a);
                    acc[i][j] = a;
                }
            }
        }
        __syncthreads();
    }

    // ---- stage logits over the (now dead) h tile ----
#pragma unroll
    for (int i = 0; i < 4; ++i)
#pragma unroll
        for (int j = 0; j < 4; ++j)
            ls[tt * 4 + i][ee * 4 + j] = acc[i][j];

    __syncthreads();

    const size_t P = (size_t)NTOK * NEXP;
    float* __restrict__ o_mask = out;
    float* __restrict__ o_prob = out + P;
    float* __restrict__ o_lc   = out + 2 * P;
    float* __restrict__ o_lsl  = out + 3 * P;
    const size_t base = (size_t)t0 * NEXP;

    // ---- vectorized writes of logits_clean / logits_sel (float4) ----
#pragma unroll
    for (int p = 0; p < 4; ++p) {
        const int g  = p * 256 + tid;         // float4 index
        const int t  = g >> 4;
        const int e4 = (g & 15) * 4;
        const float4 lv = *reinterpret_cast<const float4*>(&ls[t][e4]);
        const bool tmt = tok_mask(tmask, t0 + t, mmode);
        float4 sv;
        sv.x = tmt ? lv.x : -INFINITY;
        sv.y = tmt ? lv.y : -INFINITY;
        sv.z = tmt ? lv.z : -INFINITY;
        sv.w = tmt ? lv.w : -INFINITY;
        *reinterpret_cast<float4*>(&o_lc[base + (size_t)g * 4])  = lv;
        *reinterpret_cast<float4*>(&o_lsl[base + (size_t)g * 4]) = sv;
    }

    // ---- epilogue: wave0, one token per lane; 8-pass selection-sort top-k ----
    if (wave == 0) {
        const int lt = lane;
        const bool tm = tok_mask(tmask, t0 + lt, mmode);

        unsigned long long bits = 0ULL;
        float m0 = -INFINITY;
        for (int r = 0; r < TOPK; ++r) {
            float bv = -INFINITY; int bi = 0;
            for (int e = 0; e < 64; ++e) {
                if ((bits >> e) & 1ULL) continue;
                const float x = ls[lt][e];
                if (x > bv) { bv = x; bi = e; }
            }
            bits |= 1ULL << bi;
            if (r == 0) m0 = bv;
        }

        float ssum = 0.f;
        for (int e = 0; e < 64; ++e)
            if ((bits >> e) & 1ULL) ssum += expf(ls[lt][e] - m0);

        sm_m0[lt]  = m0;
        sm_inv[lt] = 1.0f / ssum;
        mb[lt] = tm ? bits : 0ULL;            // mb==0 encodes masked token
    }

    __syncthreads();

    // ---- vectorized writes of probs / mask (float4) ----
#pragma unroll
    for (int p = 0; p < 4; ++p) {
        const int g  = p * 256 + tid;
        const int t  = g >> 4;
        const int e4 = (g & 15) * 4;
        const float4 lv = *reinterpret_cast<const float4*>(&ls[t][e4]);
        const unsigned long long bt = mb[t];
        const float m0 = sm_m0[t], inv = sm_inv[t];
        float4 pv, mv;
        const bool s0 = (bt >> (e4 + 0)) & 1ULL;
        const bool s1 = (bt >> (e4 + 1)) & 1ULL;
        const bool s2 = (bt >> (e4 + 2)) & 1ULL;
        const bool s3 = (bt >> (e4 + 3)) & 1ULL;
        pv.x = s0 ? expf(lv.x - m0) * inv : 0.f;
        pv.y = s1 ? expf(lv.y - m0) * inv : 0.f;
        pv.z = s2 ? expf(lv.z - m0) * inv : 0.f;
        pv.w = s3 ? expf(lv.w - m0) * inv : 0.f;
        mv.x = s0 ? 1.f : 0.f;
        mv.y = s1 ? 1.f : 0.f;
        mv.z = s2 ? 1.f : 0.f;
        mv.w = s3 ? 1.f : 0.f;
        *reinterpret_cast<float4*>(&o_prob[base + (size_t)g * 4]) = pv;
        *reinterpret_cast<float4*>(&o_mask[base + (size_t)g * 4]) = mv;
    }
}

extern "C" void kernel_launch(void* const* d_in, const int* in_sizes, int n_in,
                              void* d_out, int out_size, void* d_ws, size_t ws_size,
                              hipStream_t stream)
{
    const float* h = (const float*)d_in[0];
    const float* W = (const float*)d_in[1];
    const void*  tmask = (const void*)d_in[2];
    float* out = (float*)d_out;

    hipLaunchKernelGGL(router_v16, dim3(NTOK / BTOK), dim3(256), 0, stream,
                       h, W, tmask, out);
}

// Round 17
// 731.722 us; speedup vs baseline: 1.7771x; 1.7771x over previous
//
#include <hip/hip_runtime.h>
#include <cmath>

#define NTOK 65536
#define DMOD 1024
#define NEXP 64
#define TOPK 8
#define BTOK 64                  // tokens per block
#define KCH  32                  // k-chunk per wave-private tile
#define NCH  (DMOD / KCH)        // 32 chunks
#define PSTR 33                  // private tile stride (odd)
#define LSTR 65                  // logits row stride

// token_mask may arrive as 1-byte bool or int32; sniff from the first word.
__device__ __forceinline__ bool tok_mask(const void* tm, int t, int mmode) {
    return mmode == 0 ? (((const unsigned char*)tm)[t] != 0)
                      : (((const unsigned int*)tm)[t] != 0u);
}

__global__ __launch_bounds__(256, 4)
void router_v17(const float* __restrict__ h,
                const float* __restrict__ W,
                const void* __restrict__ tmask,
                float* __restrict__ out)
{
    // 4 waves x {h-tile, W-tile} x 32x33 floats = 33.8 KB, all wave-private
    __shared__ __align__(16) float priv[4][2][32][PSTR];
    __shared__ float sm_m0[BTOK], sm_inv[BTOK];
    __shared__ unsigned long long mb[BTOK];

    // epilogue logits tile aliases the (then dead) private tiles
    float (*ls)[LSTR] = reinterpret_cast<float(*)[LSTR]>(&priv[0][0][0][0]);

    const int tid  = threadIdx.x;
    const int lane = tid & 63;
    const int wave = tid >> 6;
    const int ah   = wave >> 1;               // token half (0,1)
    const int bh   = wave & 1;                // expert half (0,1)
    const int tg   = lane & 7;                // token group: rows 4tg..4tg+3 (of 32)
    const int eg   = lane >> 3;               // expert group: rows 4eg..4eg+3 (of 32)
    const int t0   = blockIdx.x * BTOK;

    const unsigned int mw = *(const unsigned int*)tmask;
    const int mmode = (mw == 0x01010101u) ? 0 : 1;

    float (*hp)[PSTR] = priv[wave][0];        // this wave's h tile (32 rows)
    float (*wp)[PSTR] = priv[wave][1];        // this wave's W tile (32 rows)

    // staging lane map: row srow + p*8, cols scol..scol+3
    const int srow = lane >> 3;               // 0..7
    const int scol = (lane & 7) * 4;          // 0..28
    const float* hbase = h + (size_t)(t0 + ah * 32 + srow) * DMOD + scol;
    const float* wbase = W + ((size_t)(bh * 32 + srow) << 10) + scol;

    // strict sequential fp32 FMA per output, k ascending (np-ref-matching order)
    float acc[4][4];
#pragma unroll
    for (int i = 0; i < 4; ++i)
#pragma unroll
        for (int j = 0; j < 4; ++j) acc[i][j] = 0.f;

    // ---- k-loop: NO block barriers; each wave free-runs on its private tiles ----
    for (int c = 0; c < NCH; ++c) {
        const int kc = c * KCH;

        // stage this wave's h & W chunk (8 coalesced loads, 8 private LDS writes)
        float4 hg[4], wg[4];
#pragma unroll
        for (int p = 0; p < 4; ++p) {
            hg[p] = *reinterpret_cast<const float4*>(hbase + (size_t)(p * 8) * DMOD + kc);
            wg[p] = *reinterpret_cast<const float4*>(wbase + ((size_t)(p * 8) << 10) + kc);
        }
#pragma unroll
        for (int p = 0; p < 4; ++p) {
            *reinterpret_cast<float4*>(&hp[p * 8 + srow][scol]) = hg[p];
            *reinterpret_cast<float4*>(&wp[p * 8 + srow][scol]) = wg[p];
        }

        // compute: 8 windows x (8 ds_read_b128 + 64 FMA); in-wave DS ordering
        // guarantees the writes above are visible to the reads below.
#pragma unroll
        for (int k4 = 0; k4 < KCH / 4; ++k4) {
            float4 hv[4], wv[4];
#pragma unroll
            for (int i = 0; i < 4; ++i)
                hv[i] = *reinterpret_cast<const float4*>(&hp[tg * 4 + i][k4 * 4]);
#pragma unroll
            for (int j = 0; j < 4; ++j)
                wv[j] = *reinterpret_cast<const float4*>(&wp[eg * 4 + j][k4 * 4]);
#pragma unroll
            for (int i = 0; i < 4; ++i) {
#pragma unroll
                for (int j = 0; j < 4; ++j) {
                    float a = acc[i][j];
                    a = fmaf(hv[i].x, wv[j].x, a);
                    a = fmaf(hv[i].y, wv[j].y, a);
                    a = fmaf(hv[i].z, wv[j].z, a);
                    a = fmaf(hv[i].w, wv[j].w, a);
                    acc[i][j] = a;
                }
            }
        }
    }

    __syncthreads();                          // first block-wide sync since launch

    // ---- stage logits over the (now dead) private tiles ----
#pragma unroll
    for (int i = 0; i < 4; ++i)
#pragma unroll
        for (int j = 0; j < 4; ++j)
            ls[ah * 32 + tg * 4 + i][bh * 32 + eg * 4 + j] = acc[i][j];

    __syncthreads();

    const size_t P = (size_t)NTOK * NEXP;
    float* __restrict__ o_mask = out;
    float* __restrict__ o_prob = out + P;
    float* __restrict__ o_lc   = out + 2 * P;
    float* __restrict__ o_lsl  = out + 3 * P;
    const size_t base = (size_t)t0 * NEXP;

    // ---- vectorized writes of logits_clean / logits_sel (float4) ----
#pragma unroll
    for (int p = 0; p < 4; ++p) {
        const int g  = p * 256 + tid;         // float4 index
        const int t  = g >> 4;
        const int e4 = (g & 15) * 4;
        const float4 lv = *reinterpret_cast<const float4*>(&ls[t][e4]);
        const bool tmt = tok_mask(tmask, t0 + t, mmode);
        float4 sv;
        sv.x = tmt ? lv.x : -INFINITY;
        sv.y = tmt ? lv.y : -INFINITY;
        sv.z = tmt ? lv.z : -INFINITY;
        sv.w = tmt ? lv.w : -INFINITY;
        *reinterpret_cast<float4*>(&o_lc[base + (size_t)g * 4])  = lv;
        *reinterpret_cast<float4*>(&o_lsl[base + (size_t)g * 4]) = sv;
    }

    // ---- epilogue: wave0, one token per lane; 8-pass selection-sort top-k ----
    if (wave == 0) {
        const int lt = lane;
        const bool tm = tok_mask(tmask, t0 + lt, mmode);

        unsigned long long bits = 0ULL;
        float m0 = -INFINITY;
        for (int r = 0; r < TOPK; ++r) {
            float bv = -INFINITY; int bi = 0;
            for (int e = 0; e < 64; ++e) {
                if ((bits >> e) & 1ULL) continue;
                const float x = ls[lt][e];
                if (x > bv) { bv = x; bi = e; }
            }
            bits |= 1ULL << bi;
            if (r == 0) m0 = bv;
        }

        float ssum = 0.f;
        for (int e = 0; e < 64; ++e)
            if ((bits >> e) & 1ULL) ssum += expf(ls[lt][e] - m0);

        sm_m0[lt]  = m0;
        sm_inv[lt] = 1.0f / ssum;
        mb[lt] = tm ? bits : 0ULL;            // mb==0 encodes masked token
    }

    __syncthreads();

    // ---- vectorized writes of probs / mask (float4) ----
#pragma unroll
    for (int p = 0; p < 4; ++p) {
        const int g  = p * 256 + tid;
        const int t  = g >> 4;
        const int e4 = (g & 15) * 4;
        const float4 lv = *reinterpret_cast<const float4*>(&ls[t][e4]);
        const unsigned long long bt = mb[t];
        const float m0 = sm_m0[t], inv = sm_inv[t];
        float4 pv, mv;
        const bool s0 = (bt >> (e4 + 0)) & 1ULL;
        const bool s1 = (bt >> (e4 + 1)) & 1ULL;
        const bool s2 = (bt >> (e4 + 2)) & 1ULL;
        const bool s3 = (bt >> (e4 + 3)) & 1ULL;
        pv.x = s0 ? expf(lv.x - m0) * inv : 0.f;
        pv.y = s1 ? expf(lv.y - m0) * inv : 0.f;
        pv.z = s2 ? expf(lv.z - m0) * inv : 0.f;
        pv.w = s3 ? expf(lv.w - m0) * inv : 0.f;
        mv.x = s0 ? 1.f : 0.f;
        mv.y = s1 ? 1.f : 0.f;
        mv.z = s2 ? 1.f : 0.f;
        mv.w = s3 ? 1.f : 0.f;
        *reinterpret_cast<float4*>(&o_prob[base + (size_t)g * 4]) = pv;
        *reinterpret_cast<float4*>(&o_mask[base + (size_t)g * 4]) = mv;
    }
}

extern "C" void kernel_launch(void* const* d_in, const int* in_sizes, int n_in,
                              void* d_out, int out_size, void* d_ws, size_t ws_size,
                              hipStream_t stream)
{
    const float* h = (const float*)d_in[0];
    const float* W = (const float*)d_in[1];
    const void*  tmask = (const void*)d_in[2];
    float* out = (float*)d_out;

    hipLaunchKernelGGL(router_v17, dim3(NTOK / BTOK), dim3(256), 0, stream,
                       h, W, tmask, out);
}